// Round 16
// baseline (287.846 us; speedup 1.0000x reference)
//
#include <hip/hip_runtime.h>
#include <stdint.h>

#define TWO_PI_F 6.28318530717958647692f
#define INV_2PI_F 0.15915494309189535f
#define EPSF 1e-6f
#define DTF 0.01f
#define KCOUP 2.0f
#define CPL (DTF * KCOUP * INV_2PI_F)   // coupling gain in revolutions domain

// ---- GEMM geometry: BM=128, BN=224 (NTILES=3), BK=32, double-buffered LDS ----
#define BM 128
#define BN 224
#define KITERS 64                 // 2048 / 32
#define NTILES 3                  // 672 / 224, exact
#define GTHREADS 256
#define B_TILE_BYTES 14336        // 112 rows x 128B (paired cols, slot-XOR)
#define A_TILE_BYTES 16384        // 128 rows x 32 f32
#define BUF_BYTES (B_TILE_BYTES + A_TILE_BYTES)   // 30720
#define W_IMG_BYTES ((size_t)KITERS * NTILES * B_TILE_BYTES)   // 2,752,512
#define WS_NEED W_IMG_BYTES

typedef __attribute__((ext_vector_type(8)))  __bf16         bf16x8;
typedef __attribute__((ext_vector_type(8)))  unsigned short ushort8v;
typedef __attribute__((ext_vector_type(16))) float          f32x16;

__device__ __forceinline__ unsigned short f2bf(float f) {
  unsigned u = __builtin_bit_cast(unsigned, f);
  u = (u + 0x7FFFu + ((u >> 16) & 1u)) >> 16;   // RNE
  return (unsigned short)u;
}

// pack 2 f32 -> 2 bf16 (RNE, same rounding as f2bf), S0 -> low16, S1 -> high16
__device__ __forceinline__ unsigned cvtpk(float lo, float hi) {
  unsigned r;
  asm("v_cvt_pk_bf16_f32 %0, %1, %2" : "=v"(r) : "v"(lo), "v"(hi));
  return r;
}

// ---------- prep_w: W (f32) -> LDS-image bf16 [t][n][112 rows x 8 slots x 16B] ----------
// row r holds cols {2r, 2r+1} of the n-tile; logical slot q = 4*(c&1) + ls
// (ls = k-octet 0..3 within the 32-k chunk); stored at phys slot q ^ (r&7).
__global__ void prep_w(const float* __restrict__ Wd, const float* __restrict__ Wt,
                       const float* __restrict__ Wg, char* __restrict__ wbB) {
  int id = blockIdx.x * 256 + threadIdx.x;      // 672 * 64 total
  if (id >= 672 * 64) return;
  int col = id >> 6, t = id & 63;
  const float* src = (col < 32)  ? Wd + (size_t)col * 2048
                   : (col < 160) ? Wt + (size_t)(col - 32) * 2048
                                 : Wg + (size_t)(col - 160) * 2048;
  src += t * 32;
  const int n = col / BN, cin = col - n * BN;
  const int r = cin >> 1, par = cin & 1;
  char* dst = wbB + ((size_t)t * NTILES + n) * B_TILE_BYTES + r * 128;
  #pragma unroll
  for (int ls = 0; ls < 4; ls++) {
    float4 a = ((const float4*)src)[ls * 2];
    float4 b = ((const float4*)src)[ls * 2 + 1];
    ushort8v v;
    v[0] = f2bf(a.x); v[1] = f2bf(a.y); v[2] = f2bf(a.z); v[3] = f2bf(a.w);
    v[4] = f2bf(b.x); v[5] = f2bf(b.y); v[6] = f2bf(b.z); v[7] = f2bf(b.w);
    int p = (4 * par + ls) ^ (r & 7);
    *(ushort8v*)(dst + p * 16) = v;
  }
}

// ---------- K1: BN=224, dbuf LDS, stage(t+1) before counted wait on stage(t) ----------
__launch_bounds__(GTHREADS, 3)
__global__ void gemm(const float* __restrict__ x, const char* __restrict__ wbB,
                     float* __restrict__ z) {
  __shared__ __align__(16) char smem[2 * BUF_BYTES];   // 60 KB

  const int tid = threadIdx.x;
  const int wid = tid >> 6, lane = tid & 63;
  const int cl = lane & 31, hk = lane >> 5;

  // XCD-aware: 768 blocks = 8 XCD x 32 panels x 3 n-tiles; bijective
  const int bid = blockIdx.x;
  const int xcd = bid & 7, j = bid >> 3;        // j in [0,96)
  const int panel = xcd * 32 + j / NTILES;
  const int n = j % NTILES;
  const size_t row0 = (size_t)panel * BM;

  f32x16 acc[7];
  #pragma unroll
  for (int f = 0; f < 7; f++)
    #pragma unroll
    for (int jj = 0; jj < 16; jj++) acc[f][jj] = 0.f;

  // A f32 staging (r15-proven): 4 rounds; round rnd covers rows rnd*32 + (tid>>3),
  // dest = As + rnd*4096 + tid*16 (linear); source pre-swizzled by (row&7).
  const int arow_s = tid >> 3;                          // 0..31
  const int aslot_log = (tid & 7) ^ (arow_s & 7);
  const float* asrc0 = x + (row0 + arow_s) * 2048 + aslot_log * 4;

  const int arf = wid * 32 + cl;                // A frag row
  const int arf7 = arf & 7;

  const char* bimg = wbB + (size_t)n * B_TILE_BYTES;

// stage tile t into buffer buf: waves 0-1 issue 8 gll, waves 2-3 issue 7
#define STAGE(buf, t)                                                         \
  { char* Bs_ = smem + (buf) * BUF_BYTES;                                     \
    char* As_ = Bs_ + B_TILE_BYTES;                                           \
    const char* bsrc = bimg + (size_t)(t) * (NTILES * B_TILE_BYTES);          \
    _Pragma("unroll")                                                         \
    for (int rnd = 0; rnd < 3; rnd++) {                                       \
      int off = rnd * 4096 + tid * 16;                                        \
      __builtin_amdgcn_global_load_lds(                                       \
          (const __attribute__((address_space(1))) void*)(bsrc + off),        \
          (__attribute__((address_space(3))) void*)(Bs_ + off), 16, 0, 0);    \
    }                                                                         \
    if (tid < 128) {                                                          \
      int off = 12288 + tid * 16;                                             \
      __builtin_amdgcn_global_load_lds(                                       \
          (const __attribute__((address_space(1))) void*)(bsrc + off),        \
          (__attribute__((address_space(3))) void*)(Bs_ + off), 16, 0, 0);    \
    }                                                                         \
    const float* asrc = asrc0 + (t) * 32;                                     \
    _Pragma("unroll")                                                         \
    for (int rnd = 0; rnd < 4; rnd++) {                                       \
      __builtin_amdgcn_global_load_lds(                                       \
          (const __attribute__((address_space(1))) void*)(asrc + (size_t)rnd * 32 * 2048), \
          (__attribute__((address_space(3))) void*)(As_ + rnd * 4096 + tid * 16), 16, 0, 0); \
    } }

#define COMPUTE(buf)                                                          \
  { const char* Bs_ = smem + (buf) * BUF_BYTES;                               \
    const float* afb = (const float*)(Bs_ + B_TILE_BYTES + arf * 128);        \
    _Pragma("unroll")                                                         \
    for (int s4 = 0; s4 < 2; s4++) {                                          \
      int ls = s4 * 4 + hk * 2;                                               \
      int p0 = ls ^ arf7;                                                     \
      int p1 = p0 ^ 1;                                                        \
      float4 lo = *(const float4*)(afb + p0 * 4);                             \
      float4 hi = *(const float4*)(afb + p1 * 4);                             \
      unsigned d0 = cvtpk(lo.x, lo.y), d1 = cvtpk(lo.z, lo.w);                \
      unsigned d2 = cvtpk(hi.x, hi.y), d3 = cvtpk(hi.z, hi.w);                \
      uint4 u = {d0, d1, d2, d3};                                             \
      bf16x8 af = __builtin_bit_cast(bf16x8, u);                              \
      _Pragma("unroll")                                                       \
      for (int fn = 0; fn < 7; fn++) {                                        \
        int c = fn * 32 + cl;                                                 \
        int r = c >> 1;                                                       \
        int q = 4 * (c & 1) + s4 * 2 + hk;                                    \
        bf16x8 bfr = __builtin_bit_cast(bf16x8,                               \
            *(const ushort8v*)(Bs_ + r * 128 + ((q ^ (r & 7)) << 4)));        \
        acc[fn] = __builtin_amdgcn_mfma_f32_32x32x16_bf16(af, bfr, acc[fn], 0, 0, 0); } } }

  STAGE(0, 0);                                   // tile 0 in flight
  for (int t = 0; t < KITERS; t++) {
    const int cur = t & 1;
    if (t + 1 < KITERS) {
      STAGE(cur ^ 1, t + 1);                     // issue next tile first
      // outstanding: stage(t) + stage(t+1) = 16 (waves 0-1) / 14 (waves 2-3);
      // wait to <=7 retires all of stage(t) for both classes (in-order).
      asm volatile("s_waitcnt vmcnt(7)" ::: "memory");
    } else {
      asm volatile("s_waitcnt vmcnt(0)" ::: "memory");
    }
    __builtin_amdgcn_s_barrier();                // tile t visible to all waves
    __builtin_amdgcn_sched_barrier(0);
    COMPUTE(cur);
    __builtin_amdgcn_sched_barrier(0);
    __builtin_amdgcn_s_barrier();                // all reads done before buf reuse
  }
#undef STAGE
#undef COMPUTE

  #pragma unroll
  for (int fn = 0; fn < 7; fn++) {
    int col = n * BN + fn * 32 + cl;
    #pragma unroll
    for (int reg = 0; reg < 16; reg++) {
      int row = wid * 32 + (reg & 3) + ((reg >> 2) << 3) + (hk << 2);
      z[(row0 + row) * 672 + col] = acc[fn][reg];
    }
  }
}

// ---------- wave-wide f32 sum: 4 DPP levels + ds_swizzle xor16 + shfl xor32 ----------
__device__ __forceinline__ float wave_sum(float v) {
  v += __builtin_bit_cast(float, __builtin_amdgcn_update_dpp(
         0, __builtin_bit_cast(int, v), 0xB1, 0xF, 0xF, true));   // quad_perm xor1
  v += __builtin_bit_cast(float, __builtin_amdgcn_update_dpp(
         0, __builtin_bit_cast(int, v), 0x4E, 0xF, 0xF, true));   // quad_perm xor2
  v += __builtin_bit_cast(float, __builtin_amdgcn_update_dpp(
         0, __builtin_bit_cast(int, v), 0x141, 0xF, 0xF, true));  // row_half_mirror
  v += __builtin_bit_cast(float, __builtin_amdgcn_update_dpp(
         0, __builtin_bit_cast(int, v), 0x140, 0xF, 0xF, true));  // row_mirror
  v += __builtin_bit_cast(float, __builtin_amdgcn_ds_swizzle(
         __builtin_bit_cast(int, v), 0x401F));                    // xor16
  v += __shfl_xor(v, 32);                                         // cross-32
  return v;
}

// ---------- K2: Kuramoto dynamics + in-place scale of d_out ----------
#define ZSTR 164
#define DROWS 32
__launch_bounds__(256, 6)
__global__ void dyn_scale(float* __restrict__ z,
                          const float* __restrict__ pdt_p,
                          const float* __restrict__ ptg_p) {
  __shared__ float zdt[DROWS * ZSTR];
  __shared__ float Fbuf[2 * DROWS];
  const int tid = threadIdx.x;
  const int wid = tid >> 6, lane = tid & 63;
  const size_t row0 = (size_t)blockIdx.x * DROWS;

  for (int i = tid; i < DROWS * 40; i += 256) {
    int row = i / 40, c4 = i - row * 40;
    float4 v = *(const float4*)(z + (row0 + row) * 672 + c4 * 4);
    *(float4*)(&zdt[row * ZSTR + c4 * 4]) = v;
  }
  __syncthreads();

  const float pdt = fminf(fmaxf(pdt_p[0], 0.f), 1.f);
  const float ptg = fminf(fmaxf(ptg_p[0], 0.f), 1.f);

  for (int rr = 0; rr < 8; rr++) {
    int row = wid * 8 + rr;
    // phases in revolutions: q = p / 2π;  sin(p) = v_sin(fract(q))
    float pd  = ((lane < 32) ? zdt[row * ZSTR + lane] : 0.f) * INV_2PI_F;
    float pt0 = zdt[row * ZSTR + 32 + lane] * INV_2PI_F;
    float pt1 = zdt[row * ZSTR + 96 + lane] * INV_2PI_F;
    float Ft = 1.f, Fg = 1.f;
    for (int s = 0; s < 10; s++) {
      float qd = pd - floorf(pd), q0 = pt0 - floorf(pt0), q1 = pt1 - floorf(pt1);
      float sd, cd, s0, c0, s1, c1;
      asm("v_sin_f32 %0, %1" : "=v"(sd) : "v"(qd));
      asm("v_cos_f32 %0, %1" : "=v"(cd) : "v"(qd));
      asm("v_sin_f32 %0, %1" : "=v"(s0) : "v"(q0));
      asm("v_cos_f32 %0, %1" : "=v"(c0) : "v"(q0));
      asm("v_sin_f32 %0, %1" : "=v"(s1) : "v"(q1));
      asm("v_cos_f32 %0, %1" : "=v"(c1) : "v"(q1));
      float Cd = wave_sum((lane < 32) ? cd : 0.f) * (1.f / 32.f);
      float Sd = wave_sum((lane < 32) ? sd : 0.f) * (1.f / 32.f);
      float Ct = wave_sum(c0 + c1) * (1.f / 128.f);
      float St = wave_sum(s0 + s1) * (1.f / 128.f);
      pd  += DTF * 2.f + CPL * (Sd * cd - Cd * sd);
      pt0 += DTF * 6.f + CPL * (St * c0 - Ct * s0);
      pt1 += DTF * 6.f + CPL * (St * c1 - Ct * s1);
      float rdm = sqrtf(Cd * Cd + Sd * Sd) + EPSF;
      float rtm = sqrtf(Ct * Ct + St * St) + EPSF;
      Ft *= (1.f + DTF * pdt * (Cd / rdm));
      Fg *= (1.f + DTF * ptg * (Ct / rtm));
    }
    if (lane == 0) { Fbuf[row] = Ft; Fbuf[DROWS + row] = Fg; }
  }
  __syncthreads();

  // scale: cols 0..159 come from the LDS copy (no global re-read); rest from global
  for (int i = tid; i < DROWS * 168; i += 256) {
    int row = i / 168, c4 = i - row * 168;
    float4* p = (float4*)(z + (row0 + row) * 672 + c4 * 4);
    float4 v = (c4 < 40) ? *(const float4*)(&zdt[row * ZSTR + c4 * 4]) : *p;
    float f = (c4 < 8) ? 1.f : (c4 < 40 ? Fbuf[row] : Fbuf[DROWS + row]);
    v.x = fmaxf(fmaxf(fabsf(v.x), EPSF) * f, EPSF);
    v.y = fmaxf(fmaxf(fabsf(v.y), EPSF) * f, EPSF);
    v.z = fmaxf(fmaxf(fabsf(v.z), EPSF) * f, EPSF);
    v.w = fmaxf(fmaxf(fabsf(v.w), EPSF) * f, EPSF);
    *p = v;
  }
}

extern "C" void kernel_launch(void* const* d_in, const int* in_sizes, int n_in,
                              void* d_out, int out_size, void* d_ws, size_t ws_size,
                              hipStream_t stream) {
  const float* x   = (const float*)d_in[0];
  const float* Wd  = (const float*)d_in[1];
  const float* Wt  = (const float*)d_in[2];
  const float* Wg  = (const float*)d_in[3];
  const float* pdt = (const float*)d_in[4];
  const float* ptg = (const float*)d_in[5];
  float* outp = (float*)d_out;
  char* wbB = (char*)d_ws;

  if (ws_size < WS_NEED) return;

  const int Brows = in_sizes[0] / 2048;           // 32768
  prep_w<<<(672 * 64 + 255) / 256, 256, 0, stream>>>(Wd, Wt, Wg, wbB);
  gemm<<<(Brows / BM) * NTILES, GTHREADS, 0, stream>>>(x, wbB, outp);
  dyn_scale<<<Brows / DROWS, 256, 0, stream>>>(outp, pdt, ptg);
}

// Round 17
// 243.525 us; speedup vs baseline: 1.1820x; 1.1820x over previous
//
#include <hip/hip_runtime.h>
#include <stdint.h>

#define TWO_PI_F 6.28318530717958647692f
#define INV_2PI_F 0.15915494309189535f
#define EPSF 1e-6f
#define DTF 0.01f
#define KCOUP 2.0f
#define CPL (DTF * KCOUP * INV_2PI_F)   // coupling gain in revolutions domain

// ---- GEMM geometry: BM=128, BN=224, BK=16, dbuf @ 30 KB (r15 footprint) ----
#define BM 128
#define BN 224
#define KITERS 128                // 2048 / 16
#define NTILES 3                  // 672 / 224, exact
#define GTHREADS 256
#define B_TILE_BYTES 7168         // 56 lines x 128B (4 cols/line, 8 slots, XOR r&7)
#define A_TILE_BYTES 8192         // 64 lines x 128B (2 rows/line, 4 slots/row, XOR m&3)
#define BUF_BYTES (B_TILE_BYTES + A_TILE_BYTES)   // 15360; x2 = 30720
#define W_IMG_BYTES ((size_t)KITERS * NTILES * B_TILE_BYTES)   // 2,752,512
#define WS_NEED W_IMG_BYTES

typedef __attribute__((ext_vector_type(8)))  __bf16         bf16x8;
typedef __attribute__((ext_vector_type(8)))  unsigned short ushort8v;
typedef __attribute__((ext_vector_type(16))) float          f32x16;

__device__ __forceinline__ unsigned short f2bf(float f) {
  unsigned u = __builtin_bit_cast(unsigned, f);
  u = (u + 0x7FFFu + ((u >> 16) & 1u)) >> 16;   // RNE
  return (unsigned short)u;
}

// pack 2 f32 -> 2 bf16 (RNE, same rounding as f2bf), S0 -> low16, S1 -> high16
__device__ __forceinline__ unsigned cvtpk(float lo, float hi) {
  unsigned r;
  asm("v_cvt_pk_bf16_f32 %0, %1, %2" : "=v"(r) : "v"(lo), "v"(hi));
  return r;
}

// ---------- prep_w: W (f32) -> LDS-image bf16 [t][n][56 lines x 8 slots x 16B] ----------
// line r holds cols 4r..4r+3 of the n-tile; logical slot q = (c&3)*2 + ls
// (ls = k-octet 0..1 within the 16-k step); stored at phys slot q ^ (r&7).
__global__ void prep_w(const float* __restrict__ Wd, const float* __restrict__ Wt,
                       const float* __restrict__ Wg, char* __restrict__ wbB) {
  int id = blockIdx.x * 256 + threadIdx.x;      // 672 * 64 total
  if (id >= 672 * 64) return;
  int col = id >> 6, t64 = id & 63;             // t64 covers k-steps 2*t64, 2*t64+1
  const float* src = (col < 32)  ? Wd + (size_t)col * 2048
                   : (col < 160) ? Wt + (size_t)(col - 32) * 2048
                                 : Wg + (size_t)(col - 160) * 2048;
  src += t64 * 32;
  const int n = col / BN, cin = col - n * BN;
  const int r = cin >> 2, cc = cin & 3;
  #pragma unroll
  for (int ls4 = 0; ls4 < 4; ls4++) {           // octet ls4: k = t64*32 + ls4*8
    int t = t64 * 2 + (ls4 >> 1), ls = ls4 & 1;
    float4 a = ((const float4*)src)[ls4 * 2];
    float4 b = ((const float4*)src)[ls4 * 2 + 1];
    ushort8v v;
    v[0] = f2bf(a.x); v[1] = f2bf(a.y); v[2] = f2bf(a.z); v[3] = f2bf(a.w);
    v[4] = f2bf(b.x); v[5] = f2bf(b.y); v[6] = f2bf(b.z); v[7] = f2bf(b.w);
    int q = cc * 2 + ls;
    char* dst = wbB + ((size_t)t * NTILES + n) * B_TILE_BYTES + r * 128
              + ((q ^ (r & 7)) << 4);
    *(ushort8v*)dst = v;
  }
}

// ---------- K1: BK=16 double-buffered, counted vmcnt, 30 KB LDS ----------
__launch_bounds__(GTHREADS, 3)
__global__ void gemm(const float* __restrict__ x, const char* __restrict__ wbB,
                     float* __restrict__ z) {
  __shared__ __align__(16) char smem[2 * BUF_BYTES];   // 30720 B

  const int tid = threadIdx.x;
  const int wid = tid >> 6, lane = tid & 63;
  const int cl = lane & 31, hk = lane >> 5;

  // XCD-aware: 768 blocks = 8 XCD x 32 panels x 3 n-tiles; bijective
  const int bid = blockIdx.x;
  const int xcd = bid & 7, j = bid >> 3;        // j in [0,96)
  const int panel = xcd * 32 + j / NTILES;
  const int n = j % NTILES;
  const size_t row0 = (size_t)panel * BM;

  f32x16 acc[7];
  #pragma unroll
  for (int f = 0; f < 7; f++)
    #pragma unroll
    for (int jj = 0; jj < 16; jj++) acc[f][jj] = 0.f;

  // A staging: dest byte rnd*4096 + tid*16 -> line m = rnd*32 + (tid>>3),
  // half h = (tid>>2)&1, phys slot tid&3. Logical slot = (tid&3) ^ (m&3).
  // Source row = 2m + h; XOR key (tid>>3)&3 invariant across rounds.
  const int arow0 = 2 * (tid >> 3) + ((tid >> 2) & 1);
  const int aslot_log = (tid & 3) ^ ((tid >> 3) & 3);
  const float* asrc0 = x + (row0 + arow0) * 2048 + aslot_log * 4;

  // A frag read: row arf; line m = arf>>1, half = arf&1; slots {2hk,2hk+1} ^ (m&3)
  const int arf = wid * 32 + cl;
  const int akey = (arf >> 1) & 3;
  const int ahalf = arf & 1;

  const char* bimg = wbB + (size_t)n * B_TILE_BYTES;

// stage k-step t into buffer buf: waves 0-2 issue 4 gll, wave 3 issues 3
#define STAGE(buf, t)                                                         \
  { char* Bs_ = smem + (buf) * BUF_BYTES;                                     \
    char* As_ = Bs_ + B_TILE_BYTES;                                           \
    const char* bsrc = bimg + (size_t)(t) * (NTILES * B_TILE_BYTES);          \
    __builtin_amdgcn_global_load_lds(                                         \
        (const __attribute__((address_space(1))) void*)(bsrc + tid * 16),     \
        (__attribute__((address_space(3))) void*)(Bs_ + tid * 16), 16, 0, 0); \
    if (tid < 192) {                                                          \
      __builtin_amdgcn_global_load_lds(                                       \
          (const __attribute__((address_space(1))) void*)(bsrc + 4096 + tid * 16), \
          (__attribute__((address_space(3))) void*)(Bs_ + 4096 + tid * 16), 16, 0, 0); \
    }                                                                         \
    const float* asrc = asrc0 + (t) * 16;                                     \
    _Pragma("unroll")                                                         \
    for (int rnd = 0; rnd < 2; rnd++) {                                       \
      __builtin_amdgcn_global_load_lds(                                       \
          (const __attribute__((address_space(1))) void*)(asrc + (size_t)rnd * 64 * 2048), \
          (__attribute__((address_space(3))) void*)(As_ + rnd * 4096 + tid * 16), 16, 0, 0); \
    } }

#define COMPUTE(buf)                                                          \
  { const char* Bs_ = smem + (buf) * BUF_BYTES;                               \
    const char* Af_ = Bs_ + B_TILE_BYTES + (arf >> 1) * 128 + ahalf * 64;     \
    int p0 = (2 * hk) ^ akey;                                                 \
    float4 lo = *(const float4*)(Af_ + (p0 << 4));                            \
    float4 hi = *(const float4*)(Af_ + ((p0 ^ 1) << 4));                      \
    unsigned d0 = cvtpk(lo.x, lo.y), d1 = cvtpk(lo.z, lo.w);                  \
    unsigned d2 = cvtpk(hi.x, hi.y), d3 = cvtpk(hi.z, hi.w);                  \
    uint4 u = {d0, d1, d2, d3};                                               \
    bf16x8 af = __builtin_bit_cast(bf16x8, u);                                \
    _Pragma("unroll")                                                         \
    for (int fn = 0; fn < 7; fn++) {                                          \
      int c = fn * 32 + cl;                                                   \
      int r = c >> 2;                                                         \
      int q = (c & 3) * 2 + hk;                                               \
      bf16x8 bfr = __builtin_bit_cast(bf16x8,                                 \
          *(const ushort8v*)(Bs_ + r * 128 + ((q ^ (r & 7)) << 4)));          \
      acc[fn] = __builtin_amdgcn_mfma_f32_32x32x16_bf16(af, bfr, acc[fn], 0, 0, 0); } }

  STAGE(0, 0);                                   // k-step 0 in flight
  for (int t = 0; t < KITERS; t++) {
    const int cur = t & 1;
    if (t + 1 < KITERS) {
      STAGE(cur ^ 1, t + 1);                     // issue next step first
      // outstanding: stage(t)+stage(t+1) = 8 (waves 0-2) / 6 (wave 3);
      // wait to 4 / 3 retires stage(t) exactly (in-order retirement).
      if (wid < 3) { asm volatile("s_waitcnt vmcnt(4)" ::: "memory"); }
      else         { asm volatile("s_waitcnt vmcnt(3)" ::: "memory"); }
    } else {
      asm volatile("s_waitcnt vmcnt(0)" ::: "memory");
    }
    __builtin_amdgcn_s_barrier();                // step t visible to all waves
    __builtin_amdgcn_sched_barrier(0);
    COMPUTE(cur);
    __builtin_amdgcn_sched_barrier(0);
    __builtin_amdgcn_s_barrier();                // reads done before buf reuse
  }
#undef STAGE
#undef COMPUTE

  #pragma unroll
  for (int fn = 0; fn < 7; fn++) {
    int col = n * BN + fn * 32 + cl;
    #pragma unroll
    for (int reg = 0; reg < 16; reg++) {
      int row = wid * 32 + (reg & 3) + ((reg >> 2) << 3) + (hk << 2);
      z[(row0 + row) * 672 + col] = acc[fn][reg];
    }
  }
}

// ---------- wave-wide f32 sum: 4 DPP levels + ds_swizzle xor16 + shfl xor32 ----------
__device__ __forceinline__ float wave_sum(float v) {
  v += __builtin_bit_cast(float, __builtin_amdgcn_update_dpp(
         0, __builtin_bit_cast(int, v), 0xB1, 0xF, 0xF, true));   // quad_perm xor1
  v += __builtin_bit_cast(float, __builtin_amdgcn_update_dpp(
         0, __builtin_bit_cast(int, v), 0x4E, 0xF, 0xF, true));   // quad_perm xor2
  v += __builtin_bit_cast(float, __builtin_amdgcn_update_dpp(
         0, __builtin_bit_cast(int, v), 0x141, 0xF, 0xF, true));  // row_half_mirror
  v += __builtin_bit_cast(float, __builtin_amdgcn_update_dpp(
         0, __builtin_bit_cast(int, v), 0x140, 0xF, 0xF, true));  // row_mirror
  v += __builtin_bit_cast(float, __builtin_amdgcn_ds_swizzle(
         __builtin_bit_cast(int, v), 0x401F));                    // xor16
  v += __shfl_xor(v, 32);                                         // cross-32
  return v;
}

// ---------- K2: Kuramoto dynamics + in-place scale of d_out ----------
#define ZSTR 164
#define DROWS 32
__launch_bounds__(256, 6)
__global__ void dyn_scale(float* __restrict__ z,
                          const float* __restrict__ pdt_p,
                          const float* __restrict__ ptg_p) {
  __shared__ float zdt[DROWS * ZSTR];
  __shared__ float Fbuf[2 * DROWS];
  const int tid = threadIdx.x;
  const int wid = tid >> 6, lane = tid & 63;
  const size_t row0 = (size_t)blockIdx.x * DROWS;

  for (int i = tid; i < DROWS * 40; i += 256) {
    int row = i / 40, c4 = i - row * 40;
    float4 v = *(const float4*)(z + (row0 + row) * 672 + c4 * 4);
    *(float4*)(&zdt[row * ZSTR + c4 * 4]) = v;
  }
  __syncthreads();

  const float pdt = fminf(fmaxf(pdt_p[0], 0.f), 1.f);
  const float ptg = fminf(fmaxf(ptg_p[0], 0.f), 1.f);

  for (int rr = 0; rr < 8; rr++) {
    int row = wid * 8 + rr;
    // phases in revolutions: q = p / 2π;  sin(p) = v_sin(fract(q))
    float pd  = ((lane < 32) ? zdt[row * ZSTR + lane] : 0.f) * INV_2PI_F;
    float pt0 = zdt[row * ZSTR + 32 + lane] * INV_2PI_F;
    float pt1 = zdt[row * ZSTR + 96 + lane] * INV_2PI_F;
    float Ft = 1.f, Fg = 1.f;
    for (int s = 0; s < 10; s++) {
      float qd = pd - floorf(pd), q0 = pt0 - floorf(pt0), q1 = pt1 - floorf(pt1);
      float sd, cd, s0, c0, s1, c1;
      asm("v_sin_f32 %0, %1" : "=v"(sd) : "v"(qd));
      asm("v_cos_f32 %0, %1" : "=v"(cd) : "v"(qd));
      asm("v_sin_f32 %0, %1" : "=v"(s0) : "v"(q0));
      asm("v_cos_f32 %0, %1" : "=v"(c0) : "v"(q0));
      asm("v_sin_f32 %0, %1" : "=v"(s1) : "v"(q1));
      asm("v_cos_f32 %0, %1" : "=v"(c1) : "v"(q1));
      float Cd = wave_sum((lane < 32) ? cd : 0.f) * (1.f / 32.f);
      float Sd = wave_sum((lane < 32) ? sd : 0.f) * (1.f / 32.f);
      float Ct = wave_sum(c0 + c1) * (1.f / 128.f);
      float St = wave_sum(s0 + s1) * (1.f / 128.f);
      pd  += DTF * 2.f + CPL * (Sd * cd - Cd * sd);
      pt0 += DTF * 6.f + CPL * (St * c0 - Ct * s0);
      pt1 += DTF * 6.f + CPL * (St * c1 - Ct * s1);
      float rdm = sqrtf(Cd * Cd + Sd * Sd) + EPSF;
      float rtm = sqrtf(Ct * Ct + St * St) + EPSF;
      Ft *= (1.f + DTF * pdt * (Cd / rdm));
      Fg *= (1.f + DTF * ptg * (Ct / rtm));
    }
    if (lane == 0) { Fbuf[row] = Ft; Fbuf[DROWS + row] = Fg; }
  }
  __syncthreads();

  // scale: cols 0..159 come from the LDS copy (no global re-read); rest from global
  for (int i = tid; i < DROWS * 168; i += 256) {
    int row = i / 168, c4 = i - row * 168;
    float4* p = (float4*)(z + (row0 + row) * 672 + c4 * 4);
    float4 v = (c4 < 40) ? *(const float4*)(&zdt[row * ZSTR + c4 * 4]) : *p;
    float f = (c4 < 8) ? 1.f : (c4 < 40 ? Fbuf[row] : Fbuf[DROWS + row]);
    v.x = fmaxf(fmaxf(fabsf(v.x), EPSF) * f, EPSF);
    v.y = fmaxf(fmaxf(fabsf(v.y), EPSF) * f, EPSF);
    v.z = fmaxf(fmaxf(fabsf(v.z), EPSF) * f, EPSF);
    v.w = fmaxf(fmaxf(fabsf(v.w), EPSF) * f, EPSF);
    *p = v;
  }
}

extern "C" void kernel_launch(void* const* d_in, const int* in_sizes, int n_in,
                              void* d_out, int out_size, void* d_ws, size_t ws_size,
                              hipStream_t stream) {
  const float* x   = (const float*)d_in[0];
  const float* Wd  = (const float*)d_in[1];
  const float* Wt  = (const float*)d_in[2];
  const float* Wg  = (const float*)d_in[3];
  const float* pdt = (const float*)d_in[4];
  const float* ptg = (const float*)d_in[5];
  float* outp = (float*)d_out;
  char* wbB = (char*)d_ws;

  if (ws_size < WS_NEED) return;

  const int Brows = in_sizes[0] / 2048;           // 32768
  prep_w<<<(672 * 64 + 255) / 256, 256, 0, stream>>>(Wd, Wt, Wg, wbB);
  gemm<<<(Brows / BM) * NTILES, GTHREADS, 0, stream>>>(x, wbB, outp);
  dyn_scale<<<Brows / DROWS, 256, 0, stream>>>(outp, pdt, ptg);
}

// Round 18
// 229.265 us; speedup vs baseline: 1.2555x; 1.0622x over previous
//
#include <hip/hip_runtime.h>
#include <stdint.h>

#define TWO_PI_F 6.28318530717958647692f
#define INV_2PI_F 0.15915494309189535f
#define EPSF 1e-6f
#define DTF 0.01f
#define KCOUP 2.0f
#define CPL (DTF * KCOUP * INV_2PI_F)   // coupling gain in revolutions domain

// ---- GEMM geometry: BM=128, BN=224 (NTILES=3), BK=32 (r15 measured-best) ----
#define BM 128
#define BN 224
#define KITERS 64                 // 2048 / 32
#define NTILES 3                  // 672 / 224, exact
#define GTHREADS 256
#define B_TILE_BYTES 14336        // 112 rows x 128B (paired cols, slot-XOR)
#define A_TILE_BYTES 16384        // 128 rows x 32 f32
#define W_IMG_BYTES ((size_t)KITERS * NTILES * B_TILE_BYTES)   // 2,752,512
#define WS_NEED W_IMG_BYTES

typedef __attribute__((ext_vector_type(8)))  __bf16         bf16x8;
typedef __attribute__((ext_vector_type(8)))  unsigned short ushort8v;
typedef __attribute__((ext_vector_type(16))) float          f32x16;

__device__ __forceinline__ unsigned short f2bf(float f) {
  unsigned u = __builtin_bit_cast(unsigned, f);
  u = (u + 0x7FFFu + ((u >> 16) & 1u)) >> 16;   // RNE
  return (unsigned short)u;
}

// pack 2 f32 -> 2 bf16 (RNE, same rounding as f2bf), S0 -> low16, S1 -> high16
__device__ __forceinline__ unsigned cvtpk(float lo, float hi) {
  unsigned r;
  asm("v_cvt_pk_bf16_f32 %0, %1, %2" : "=v"(r) : "v"(lo), "v"(hi));
  return r;
}

// ---------- prep_w: W (f32) -> LDS-image bf16 [t][n][112 rows x 8 slots x 16B] ----------
// row r holds cols {2r, 2r+1} of the n-tile; logical slot q = 4*(c&1) + ls
// (ls = k-octet 0..3 within the 32-k chunk); stored at phys slot q ^ (r&7).
__global__ void prep_w(const float* __restrict__ Wd, const float* __restrict__ Wt,
                       const float* __restrict__ Wg, char* __restrict__ wbB) {
  int id = blockIdx.x * 256 + threadIdx.x;      // 672 * 64 total
  if (id >= 672 * 64) return;
  int col = id >> 6, t = id & 63;
  const float* src = (col < 32)  ? Wd + (size_t)col * 2048
                   : (col < 160) ? Wt + (size_t)(col - 32) * 2048
                                 : Wg + (size_t)(col - 160) * 2048;
  src += t * 32;
  const int n = col / BN, cin = col - n * BN;
  const int r = cin >> 1, par = cin & 1;
  char* dst = wbB + ((size_t)t * NTILES + n) * B_TILE_BYTES + r * 128;
  #pragma unroll
  for (int ls = 0; ls < 4; ls++) {
    float4 a = ((const float4*)src)[ls * 2];
    float4 b = ((const float4*)src)[ls * 2 + 1];
    ushort8v v;
    v[0] = f2bf(a.x); v[1] = f2bf(a.y); v[2] = f2bf(a.z); v[3] = f2bf(a.w);
    v[4] = f2bf(b.x); v[5] = f2bf(b.y); v[6] = f2bf(b.z); v[7] = f2bf(b.w);
    int p = (4 * par + ls) ^ (r & 7);
    *(ushort8v*)(dst + p * 16) = v;
  }
}

// ---------- K1: BN=224, A f32 + B bf16 via global_load_lds (A issued first) ----------
__launch_bounds__(GTHREADS, 3)
__global__ void gemm(const float* __restrict__ x, const char* __restrict__ wbB,
                     float* __restrict__ z) {
  __shared__ __align__(16) char smem[B_TILE_BYTES + A_TILE_BYTES];   // 30 KB
  char* Bs = smem;
  char* As = smem + B_TILE_BYTES;

  const int tid = threadIdx.x;
  const int wid = tid >> 6, lane = tid & 63;
  const int cl = lane & 31, hk = lane >> 5;

  // XCD-aware: 768 blocks = 8 XCD x 32 panels x 3 n-tiles; bijective
  const int bid = blockIdx.x;
  const int xcd = bid & 7, j = bid >> 3;        // j in [0,96)
  const int panel = xcd * 32 + j / NTILES;
  const int n = j % NTILES;
  const size_t row0 = (size_t)panel * BM;

  f32x16 acc[7];
  #pragma unroll
  for (int f = 0; f < 7; f++)
    #pragma unroll
    for (int jj = 0; jj < 16; jj++) acc[f][jj] = 0.f;

  // A f32 staging: 4 rounds; round rnd covers rows rnd*32 + (tid>>3),
  // dest = As + rnd*4096 + tid*16 (linear); source pre-swizzled by (row&7).
  const int arow_s = tid >> 3;                          // 0..31
  const int aslot_log = (tid & 7) ^ (arow_s & 7);
  const float* asrc0 = x + (row0 + arow_s) * 2048 + aslot_log * 4;

  // A frag read: row = wid*32 + cl, stride 128B, phys slot = ls ^ (row&7)
  const int arf = wid * 32 + cl;
  const float* afbase = (const float*)(As + arf * 128);
  const int arf7 = arf & 7;

  const char* bimg = wbB + (size_t)n * B_TILE_BYTES;

  for (int t = 0; t < KITERS; t++) {
    __syncthreads();                              // prev compute done, LDS free
    {
      // A first: longer-latency (L3) batch gets max headroom before the drain
      const float* asrc = asrc0 + t * 32;
      #pragma unroll
      for (int rnd = 0; rnd < 4; rnd++) {
        __builtin_amdgcn_global_load_lds(
            (const __attribute__((address_space(1))) void*)(asrc + (size_t)rnd * 32 * 2048),
            (__attribute__((address_space(3))) void*)(As + rnd * 4096 + tid * 16), 16, 0, 0);
      }
      const char* bsrc = bimg + (size_t)t * (NTILES * B_TILE_BYTES);
      #pragma unroll
      for (int rnd = 0; rnd < 3; rnd++) {
        int off = rnd * 4096 + tid * 16;
        __builtin_amdgcn_global_load_lds(
            (const __attribute__((address_space(1))) void*)(bsrc + off),
            (__attribute__((address_space(3))) void*)(Bs + off), 16, 0, 0);
      }
      if (tid < 128) {
        int off = 12288 + tid * 16;
        __builtin_amdgcn_global_load_lds(
            (const __attribute__((address_space(1))) void*)(bsrc + off),
            (__attribute__((address_space(3))) void*)(Bs + off), 16, 0, 0);
      }
    }
    __syncthreads();                              // staged tiles visible (vmcnt drained)
    #pragma unroll
    for (int s4 = 0; s4 < 2; s4++) {
      // A: two b128 reads (8 f32, k = s4*16 + hk*8 .. +7), swizzled slots
      int ls = s4 * 4 + hk * 2;
      int p0 = ls ^ arf7;
      int p1 = p0 ^ 1;                            // ls even
      float4 lo = *(const float4*)(afbase + p0 * 4);
      float4 hi = *(const float4*)(afbase + p1 * 4);
      unsigned d0 = cvtpk(lo.x, lo.y), d1 = cvtpk(lo.z, lo.w);
      unsigned d2 = cvtpk(hi.x, hi.y), d3 = cvtpk(hi.z, hi.w);
      uint4 u = {d0, d1, d2, d3};
      bf16x8 af = __builtin_bit_cast(bf16x8, u);
      #pragma unroll
      for (int fn = 0; fn < 7; fn++) {
        int c = fn * 32 + cl;
        int r = c >> 1;
        int q = 4 * (c & 1) + s4 * 2 + hk;
        bf16x8 bfr = __builtin_bit_cast(bf16x8,
            *(const ushort8v*)(Bs + r * 128 + ((q ^ (r & 7)) << 4)));
        acc[fn] = __builtin_amdgcn_mfma_f32_32x32x16_bf16(af, bfr, acc[fn], 0, 0, 0);
      }
    }
  }

  #pragma unroll
  for (int fn = 0; fn < 7; fn++) {
    int col = n * BN + fn * 32 + cl;
    #pragma unroll
    for (int reg = 0; reg < 16; reg++) {
      int row = wid * 32 + (reg & 3) + ((reg >> 2) << 3) + (hk << 2);
      z[(row0 + row) * 672 + col] = acc[fn][reg];
    }
  }
}

// ---------- wave-wide f32 sum: 4 DPP levels + ds_swizzle xor16 + shfl xor32 ----------
__device__ __forceinline__ float wave_sum(float v) {
  v += __builtin_bit_cast(float, __builtin_amdgcn_update_dpp(
         0, __builtin_bit_cast(int, v), 0xB1, 0xF, 0xF, true));   // quad_perm xor1
  v += __builtin_bit_cast(float, __builtin_amdgcn_update_dpp(
         0, __builtin_bit_cast(int, v), 0x4E, 0xF, 0xF, true));   // quad_perm xor2
  v += __builtin_bit_cast(float, __builtin_amdgcn_update_dpp(
         0, __builtin_bit_cast(int, v), 0x141, 0xF, 0xF, true));  // row_half_mirror
  v += __builtin_bit_cast(float, __builtin_amdgcn_update_dpp(
         0, __builtin_bit_cast(int, v), 0x140, 0xF, 0xF, true));  // row_mirror
  v += __builtin_bit_cast(float, __builtin_amdgcn_ds_swizzle(
         __builtin_bit_cast(int, v), 0x401F));                    // xor16
  v += __shfl_xor(v, 32);                                         // cross-32
  return v;
}

// ---------- K2: Kuramoto dynamics + in-place scale of d_out ----------
#define ZSTR 164
#define DROWS 32
__launch_bounds__(256, 6)
__global__ void dyn_scale(float* __restrict__ z,
                          const float* __restrict__ pdt_p,
                          const float* __restrict__ ptg_p) {
  __shared__ float zdt[DROWS * ZSTR];
  __shared__ float Fbuf[2 * DROWS];
  const int tid = threadIdx.x;
  const int wid = tid >> 6, lane = tid & 63;
  const size_t row0 = (size_t)blockIdx.x * DROWS;

  for (int i = tid; i < DROWS * 40; i += 256) {
    int row = i / 40, c4 = i - row * 40;
    float4 v = *(const float4*)(z + (row0 + row) * 672 + c4 * 4);
    *(float4*)(&zdt[row * ZSTR + c4 * 4]) = v;
  }
  __syncthreads();

  const float pdt = fminf(fmaxf(pdt_p[0], 0.f), 1.f);
  const float ptg = fminf(fmaxf(ptg_p[0], 0.f), 1.f);

  for (int rr = 0; rr < 8; rr++) {
    int row = wid * 8 + rr;
    // phases in revolutions: q = p / 2π;  sin(p) = v_sin(fract(q))
    float pd  = ((lane < 32) ? zdt[row * ZSTR + lane] : 0.f) * INV_2PI_F;
    float pt0 = zdt[row * ZSTR + 32 + lane] * INV_2PI_F;
    float pt1 = zdt[row * ZSTR + 96 + lane] * INV_2PI_F;
    float Ft = 1.f, Fg = 1.f;
    for (int s = 0; s < 10; s++) {
      float qd = pd - floorf(pd), q0 = pt0 - floorf(pt0), q1 = pt1 - floorf(pt1);
      float sd, cd, s0, c0, s1, c1;
      asm("v_sin_f32 %0, %1" : "=v"(sd) : "v"(qd));
      asm("v_cos_f32 %0, %1" : "=v"(cd) : "v"(qd));
      asm("v_sin_f32 %0, %1" : "=v"(s0) : "v"(q0));
      asm("v_cos_f32 %0, %1" : "=v"(c0) : "v"(q0));
      asm("v_sin_f32 %0, %1" : "=v"(s1) : "v"(q1));
      asm("v_cos_f32 %0, %1" : "=v"(c1) : "v"(q1));
      float Cd = wave_sum((lane < 32) ? cd : 0.f) * (1.f / 32.f);
      float Sd = wave_sum((lane < 32) ? sd : 0.f) * (1.f / 32.f);
      float Ct = wave_sum(c0 + c1) * (1.f / 128.f);
      float St = wave_sum(s0 + s1) * (1.f / 128.f);
      pd  += DTF * 2.f + CPL * (Sd * cd - Cd * sd);
      pt0 += DTF * 6.f + CPL * (St * c0 - Ct * s0);
      pt1 += DTF * 6.f + CPL * (St * c1 - Ct * s1);
      float rdm = sqrtf(Cd * Cd + Sd * Sd) + EPSF;
      float rtm = sqrtf(Ct * Ct + St * St) + EPSF;
      Ft *= (1.f + DTF * pdt * (Cd / rdm));
      Fg *= (1.f + DTF * ptg * (Ct / rtm));
    }
    if (lane == 0) { Fbuf[row] = Ft; Fbuf[DROWS + row] = Fg; }
  }
  __syncthreads();

  // scale: cols 0..159 come from the LDS copy (no global re-read); rest from global
  for (int i = tid; i < DROWS * 168; i += 256) {
    int row = i / 168, c4 = i - row * 168;
    float4* p = (float4*)(z + (row0 + row) * 672 + c4 * 4);
    float4 v = (c4 < 40) ? *(const float4*)(&zdt[row * ZSTR + c4 * 4]) : *p;
    float f = (c4 < 8) ? 1.f : (c4 < 40 ? Fbuf[row] : Fbuf[DROWS + row]);
    v.x = fmaxf(fmaxf(fabsf(v.x), EPSF) * f, EPSF);
    v.y = fmaxf(fmaxf(fabsf(v.y), EPSF) * f, EPSF);
    v.z = fmaxf(fmaxf(fabsf(v.z), EPSF) * f, EPSF);
    v.w = fmaxf(fmaxf(fabsf(v.w), EPSF) * f, EPSF);
    *p = v;
  }
}

extern "C" void kernel_launch(void* const* d_in, const int* in_sizes, int n_in,
                              void* d_out, int out_size, void* d_ws, size_t ws_size,
                              hipStream_t stream) {
  const float* x   = (const float*)d_in[0];
  const float* Wd  = (const float*)d_in[1];
  const float* Wt  = (const float*)d_in[2];
  const float* Wg  = (const float*)d_in[3];
  const float* pdt = (const float*)d_in[4];
  const float* ptg = (const float*)d_in[5];
  float* outp = (float*)d_out;
  char* wbB = (char*)d_ws;

  if (ws_size < WS_NEED) return;

  const int Brows = in_sizes[0] / 2048;           // 32768
  prep_w<<<(672 * 64 + 255) / 256, 256, 0, stream>>>(Wd, Wt, Wg, wbB);
  gemm<<<(Brows / BM) * NTILES, GTHREADS, 0, stream>>>(x, wbB, outp);
  dyn_scale<<<Brows / DROWS, 256, 0, stream>>>(outp, pdt, ptg);
}

// Round 19
// 214.467 us; speedup vs baseline: 1.3421x; 1.0690x over previous
//
#include <hip/hip_runtime.h>
#include <stdint.h>

#define TWO_PI_F 6.28318530717958647692f
#define INV_2PI_F 0.15915494309189535f
#define EPSF 1e-6f
#define DTF 0.01f
#define KCOUP 2.0f
#define CPL (DTF * KCOUP * INV_2PI_F)   // coupling gain in revolutions domain

// ---- GEMM geometry: BM=128, BN=224 (NTILES=3), BK=32 (r15 measured-best) ----
#define BM 128
#define BN 224
#define KITERS 64                 // 2048 / 32
#define NTILES 3                  // 672 / 224, exact
#define GTHREADS 256
#define B_TILE_BYTES 14336        // 112 rows x 128B (paired cols, slot-XOR)
#define A_TILE_BYTES 16384        // 128 rows x 32 f32
#define W_IMG_BYTES ((size_t)KITERS * NTILES * B_TILE_BYTES)   // 2,752,512
#define WS_NEED W_IMG_BYTES

typedef __attribute__((ext_vector_type(8)))  __bf16         bf16x8;
typedef __attribute__((ext_vector_type(8)))  unsigned short ushort8v;
typedef __attribute__((ext_vector_type(16))) float          f32x16;

__device__ __forceinline__ unsigned short f2bf(float f) {
  unsigned u = __builtin_bit_cast(unsigned, f);
  u = (u + 0x7FFFu + ((u >> 16) & 1u)) >> 16;   // RNE
  return (unsigned short)u;
}

// pack 2 f32 -> 2 bf16 (RNE, same rounding as f2bf), S0 -> low16, S1 -> high16
__device__ __forceinline__ unsigned cvtpk(float lo, float hi) {
  unsigned r;
  asm("v_cvt_pk_bf16_f32 %0, %1, %2" : "=v"(r) : "v"(lo), "v"(hi));
  return r;
}

// ---------- prep_w: W (f32) -> LDS-image bf16 [t][n][112 rows x 8 slots x 16B] ----------
// row r holds cols {2r, 2r+1} of the n-tile; logical slot q = 4*(c&1) + ls
// (ls = k-octet 0..3 within the 32-k chunk); stored at phys slot q ^ (r&7).
__global__ void prep_w(const float* __restrict__ Wd, const float* __restrict__ Wt,
                       const float* __restrict__ Wg, char* __restrict__ wbB) {
  int id = blockIdx.x * 256 + threadIdx.x;      // 672 * 64 total
  if (id >= 672 * 64) return;
  int col = id >> 6, t = id & 63;
  const float* src = (col < 32)  ? Wd + (size_t)col * 2048
                   : (col < 160) ? Wt + (size_t)(col - 32) * 2048
                                 : Wg + (size_t)(col - 160) * 2048;
  src += t * 32;
  const int n = col / BN, cin = col - n * BN;
  const int r = cin >> 1, par = cin & 1;
  char* dst = wbB + ((size_t)t * NTILES + n) * B_TILE_BYTES + r * 128;
  #pragma unroll
  for (int ls = 0; ls < 4; ls++) {
    float4 a = ((const float4*)src)[ls * 2];
    float4 b = ((const float4*)src)[ls * 2 + 1];
    ushort8v v;
    v[0] = f2bf(a.x); v[1] = f2bf(a.y); v[2] = f2bf(a.z); v[3] = f2bf(a.w);
    v[4] = f2bf(b.x); v[5] = f2bf(b.y); v[6] = f2bf(b.z); v[7] = f2bf(b.w);
    int p = (4 * par + ls) ^ (r & 7);
    *(ushort8v*)(dst + p * 16) = v;
  }
}

// ---------- K1 (r15 exact): BN=224, A f32 + B bf16 via global_load_lds ----------
__launch_bounds__(GTHREADS, 3)
__global__ void gemm(const float* __restrict__ x, const char* __restrict__ wbB,
                     float* __restrict__ z) {
  __shared__ __align__(16) char smem[B_TILE_BYTES + A_TILE_BYTES];   // 30 KB
  char* Bs = smem;
  char* As = smem + B_TILE_BYTES;

  const int tid = threadIdx.x;
  const int wid = tid >> 6, lane = tid & 63;
  const int cl = lane & 31, hk = lane >> 5;

  // XCD-aware: 768 blocks = 8 XCD x 32 panels x 3 n-tiles; bijective
  const int bid = blockIdx.x;
  const int xcd = bid & 7, j = bid >> 3;        // j in [0,96)
  const int panel = xcd * 32 + j / NTILES;
  const int n = j % NTILES;
  const size_t row0 = (size_t)panel * BM;

  f32x16 acc[7];
  #pragma unroll
  for (int f = 0; f < 7; f++)
    #pragma unroll
    for (int jj = 0; jj < 16; jj++) acc[f][jj] = 0.f;

  // A f32 staging: 4 rounds; round rnd covers rows rnd*32 + (tid>>3),
  // dest = As + rnd*4096 + tid*16 (linear); source pre-swizzled by (row&7).
  const int arow_s = tid >> 3;                          // 0..31
  const int aslot_log = (tid & 7) ^ (arow_s & 7);
  const float* asrc0 = x + (row0 + arow_s) * 2048 + aslot_log * 4;

  // A frag read: row = wid*32 + cl, stride 128B, phys slot = ls ^ (row&7)
  const int arf = wid * 32 + cl;
  const float* afbase = (const float*)(As + arf * 128);
  const int arf7 = arf & 7;

  const char* bimg = wbB + (size_t)n * B_TILE_BYTES;

  for (int t = 0; t < KITERS; t++) {
    __syncthreads();                              // prev compute done, LDS free
    {
      const char* bsrc = bimg + (size_t)t * (NTILES * B_TILE_BYTES);
      #pragma unroll
      for (int rnd = 0; rnd < 3; rnd++) {
        int off = rnd * 4096 + tid * 16;
        __builtin_amdgcn_global_load_lds(
            (const __attribute__((address_space(1))) void*)(bsrc + off),
            (__attribute__((address_space(3))) void*)(Bs + off), 16, 0, 0);
      }
      if (tid < 128) {
        int off = 12288 + tid * 16;
        __builtin_amdgcn_global_load_lds(
            (const __attribute__((address_space(1))) void*)(bsrc + off),
            (__attribute__((address_space(3))) void*)(Bs + off), 16, 0, 0);
      }
      const float* asrc = asrc0 + t * 32;
      #pragma unroll
      for (int rnd = 0; rnd < 4; rnd++) {
        __builtin_amdgcn_global_load_lds(
            (const __attribute__((address_space(1))) void*)(asrc + (size_t)rnd * 32 * 2048),
            (__attribute__((address_space(3))) void*)(As + rnd * 4096 + tid * 16), 16, 0, 0);
      }
    }
    __syncthreads();                              // staged tiles visible (vmcnt drained)
    #pragma unroll
    for (int s4 = 0; s4 < 2; s4++) {
      // A: two b128 reads (8 f32, k = s4*16 + hk*8 .. +7), swizzled slots
      int ls = s4 * 4 + hk * 2;
      int p0 = ls ^ arf7;
      int p1 = p0 ^ 1;                            // ls even
      float4 lo = *(const float4*)(afbase + p0 * 4);
      float4 hi = *(const float4*)(afbase + p1 * 4);
      unsigned d0 = cvtpk(lo.x, lo.y), d1 = cvtpk(lo.z, lo.w);
      unsigned d2 = cvtpk(hi.x, hi.y), d3 = cvtpk(hi.z, hi.w);
      uint4 u = {d0, d1, d2, d3};
      bf16x8 af = __builtin_bit_cast(bf16x8, u);
      #pragma unroll
      for (int fn = 0; fn < 7; fn++) {
        int c = fn * 32 + cl;
        int r = c >> 1;
        int q = 4 * (c & 1) + s4 * 2 + hk;
        bf16x8 bfr = __builtin_bit_cast(bf16x8,
            *(const ushort8v*)(Bs + r * 128 + ((q ^ (r & 7)) << 4)));
        acc[fn] = __builtin_amdgcn_mfma_f32_32x32x16_bf16(af, bfr, acc[fn], 0, 0, 0);
      }
    }
  }

  #pragma unroll
  for (int fn = 0; fn < 7; fn++) {
    int col = n * BN + fn * 32 + cl;
    #pragma unroll
    for (int reg = 0; reg < 16; reg++) {
      int row = wid * 32 + (reg & 3) + ((reg >> 2) << 3) + (hk << 2);
      z[(row0 + row) * 672 + col] = acc[fn][reg];
    }
  }
}

// ---------- wave-wide f32 sum: 4 DPP levels + ds_swizzle xor16 + shfl xor32 ----------
__device__ __forceinline__ float wave_sum(float v) {
  v += __builtin_bit_cast(float, __builtin_amdgcn_update_dpp(
         0, __builtin_bit_cast(int, v), 0xB1, 0xF, 0xF, true));   // quad_perm xor1
  v += __builtin_bit_cast(float, __builtin_amdgcn_update_dpp(
         0, __builtin_bit_cast(int, v), 0x4E, 0xF, 0xF, true));   // quad_perm xor2
  v += __builtin_bit_cast(float, __builtin_amdgcn_update_dpp(
         0, __builtin_bit_cast(int, v), 0x141, 0xF, 0xF, true));  // row_half_mirror
  v += __builtin_bit_cast(float, __builtin_amdgcn_update_dpp(
         0, __builtin_bit_cast(int, v), 0x140, 0xF, 0xF, true));  // row_mirror
  v += __builtin_bit_cast(float, __builtin_amdgcn_ds_swizzle(
         __builtin_bit_cast(int, v), 0x401F));                    // xor16
  v += __shfl_xor(v, 32);                                         // cross-32
  return v;
}

// ---------- K2: Kuramoto dynamics + in-place scale (DROWS=16 for overlap) ----------
#define ZSTR 164
#define DROWS 16
__launch_bounds__(256, 6)
__global__ void dyn_scale(float* __restrict__ z,
                          const float* __restrict__ pdt_p,
                          const float* __restrict__ ptg_p) {
  __shared__ float zdt[DROWS * ZSTR];
  __shared__ float Fbuf[2 * DROWS];
  const int tid = threadIdx.x;
  const int wid = tid >> 6, lane = tid & 63;
  const size_t row0 = (size_t)blockIdx.x * DROWS;

  for (int i = tid; i < DROWS * 40; i += 256) {
    int row = i / 40, c4 = i - row * 40;
    float4 v = *(const float4*)(z + (row0 + row) * 672 + c4 * 4);
    *(float4*)(&zdt[row * ZSTR + c4 * 4]) = v;
  }
  __syncthreads();

  const float pdt = fminf(fmaxf(pdt_p[0], 0.f), 1.f);
  const float ptg = fminf(fmaxf(ptg_p[0], 0.f), 1.f);

  for (int rr = 0; rr < 4; rr++) {               // each wave: 4 rows
    int row = wid * 4 + rr;
    // phases in revolutions: q = p / 2π;  sin(p) = v_sin(fract(q))
    float pd  = ((lane < 32) ? zdt[row * ZSTR + lane] : 0.f) * INV_2PI_F;
    float pt0 = zdt[row * ZSTR + 32 + lane] * INV_2PI_F;
    float pt1 = zdt[row * ZSTR + 96 + lane] * INV_2PI_F;
    float Ft = 1.f, Fg = 1.f;
    for (int s = 0; s < 10; s++) {
      float qd = pd - floorf(pd), q0 = pt0 - floorf(pt0), q1 = pt1 - floorf(pt1);
      float sd, cd, s0, c0, s1, c1;
      asm("v_sin_f32 %0, %1" : "=v"(sd) : "v"(qd));
      asm("v_cos_f32 %0, %1" : "=v"(cd) : "v"(qd));
      asm("v_sin_f32 %0, %1" : "=v"(s0) : "v"(q0));
      asm("v_cos_f32 %0, %1" : "=v"(c0) : "v"(q0));
      asm("v_sin_f32 %0, %1" : "=v"(s1) : "v"(q1));
      asm("v_cos_f32 %0, %1" : "=v"(c1) : "v"(q1));
      float Cd = wave_sum((lane < 32) ? cd : 0.f) * (1.f / 32.f);
      float Sd = wave_sum((lane < 32) ? sd : 0.f) * (1.f / 32.f);
      float Ct = wave_sum(c0 + c1) * (1.f / 128.f);
      float St = wave_sum(s0 + s1) * (1.f / 128.f);
      pd  += DTF * 2.f + CPL * (Sd * cd - Cd * sd);
      pt0 += DTF * 6.f + CPL * (St * c0 - Ct * s0);
      pt1 += DTF * 6.f + CPL * (St * c1 - Ct * s1);
      float rdm = sqrtf(Cd * Cd + Sd * Sd) + EPSF;
      float rtm = sqrtf(Ct * Ct + St * St) + EPSF;
      Ft *= (1.f + DTF * pdt * (Cd / rdm));
      Fg *= (1.f + DTF * ptg * (Ct / rtm));
    }
    if (lane == 0) { Fbuf[row] = Ft; Fbuf[DROWS + row] = Fg; }
  }
  __syncthreads();

  // scale: cols 0..159 come from the LDS copy (no global re-read); rest from global
  for (int i = tid; i < DROWS * 168; i += 256) {
    int row = i / 168, c4 = i - row * 168;
    float4* p = (float4*)(z + (row0 + row) * 672 + c4 * 4);
    float4 v = (c4 < 40) ? *(const float4*)(&zdt[row * ZSTR + c4 * 4]) : *p;
    float f = (c4 < 8) ? 1.f : (c4 < 40 ? Fbuf[row] : Fbuf[DROWS + row]);
    v.x = fmaxf(fmaxf(fabsf(v.x), EPSF) * f, EPSF);
    v.y = fmaxf(fmaxf(fabsf(v.y), EPSF) * f, EPSF);
    v.z = fmaxf(fmaxf(fabsf(v.z), EPSF) * f, EPSF);
    v.w = fmaxf(fmaxf(fabsf(v.w), EPSF) * f, EPSF);
    *p = v;
  }
}

extern "C" void kernel_launch(void* const* d_in, const int* in_sizes, int n_in,
                              void* d_out, int out_size, void* d_ws, size_t ws_size,
                              hipStream_t stream) {
  const float* x   = (const float*)d_in[0];
  const float* Wd  = (const float*)d_in[1];
  const float* Wt  = (const float*)d_in[2];
  const float* Wg  = (const float*)d_in[3];
  const float* pdt = (const float*)d_in[4];
  const float* ptg = (const float*)d_in[5];
  float* outp = (float*)d_out;
  char* wbB = (char*)d_ws;

  if (ws_size < WS_NEED) return;

  const int Brows = in_sizes[0] / 2048;           // 32768
  prep_w<<<(672 * 64 + 255) / 256, 256, 0, stream>>>(Wd, Wt, Wg, wbB);
  gemm<<<(Brows / BM) * NTILES, GTHREADS, 0, stream>>>(x, wbB, outp);
  dyn_scale<<<Brows / DROWS, 256, 0, stream>>>(outp, pdt, ptg);
}